// Round 4
// baseline (1330.210 us; speedup 1.0000x reference)
//
#include <hip/hip_runtime.h>
#include <hip/hip_bf16.h>
#include <cstdint>
#include <math.h>

#define N_TOK 8192
#define D_DIM 1024
#define F_DIM 4096
#define NE 8
#define CAP 8192

typedef __attribute__((ext_vector_type(8))) short short8;
typedef __attribute__((ext_vector_type(4))) short short4v;
typedef __attribute__((ext_vector_type(4))) float f32x4;

__device__ __forceinline__ short f2bf(float f) {
  __bf16 b = (__bf16)f;
  return *(short*)&b;
}

// ---------------- gating: fp32 logits, top-2, renormalize, bucket scatter ----
__global__ __launch_bounds__(256) void gate_kernel(
    const float* __restrict__ X, const float* __restrict__ Wg,
    const float* __restrict__ bg, int* __restrict__ cnt,
    int* __restrict__ bucket, float* __restrict__ pairw)
{
  const int token = blockIdx.x;
  const int tid = threadIdx.x;
  const float4* x4 = (const float4*)(X + (size_t)token * D_DIM);
  const float4* wg4 = (const float4*)Wg;
  float part[NE];
#pragma unroll
  for (int e = 0; e < NE; ++e) part[e] = 0.f;
  {
    const float4 xv = x4[tid];                       // 256 thr x 4 = 1024
#pragma unroll
    for (int e = 0; e < NE; ++e) {
      const float4 wv = wg4[e * (D_DIM / 4) + tid];
      part[e] = fmaf(xv.x, wv.x, fmaf(xv.y, wv.y, fmaf(xv.z, wv.z, fmaf(xv.w, wv.w, part[e]))));
    }
  }
#pragma unroll
  for (int e = 0; e < NE; ++e) {
#pragma unroll
    for (int off = 32; off > 0; off >>= 1) part[e] += __shfl_down(part[e], off);
  }
  __shared__ float wsum[4][NE];
  const int wave = tid >> 6;
  if ((tid & 63) == 0) {
#pragma unroll
    for (int e = 0; e < NE; ++e) wsum[wave][e] = part[e];
  }
  __syncthreads();
  if (tid == 0) {
    float lg[NE];
#pragma unroll
    for (int e = 0; e < NE; ++e)
      lg[e] = wsum[0][e] + wsum[1][e] + wsum[2][e] + wsum[3][e] + bg[e];
    int e0 = 0;
#pragma unroll
    for (int e = 1; e < NE; ++e) if (lg[e] > lg[e0]) e0 = e;     // jax tie-break: lower idx
    int e1 = (e0 == 0) ? 1 : 0;
#pragma unroll
    for (int e = 0; e < NE; ++e) if (e != e0 && lg[e] > lg[e1]) e1 = e;
    float p1 = expf(lg[e1] - lg[e0]);            // p0 = 1; softmax denom cancels
    float inv = 1.f / (1.f + p1);
    pairw[token * 2]     = inv;
    pairw[token * 2 + 1] = p1 * inv;
    int pos0 = atomicAdd(&cnt[e0], 1);
    bucket[e0 * CAP + pos0] = token * 2;
    int pos1 = atomicAdd(&cnt[e1], 1);
    bucket[e1 * CAP + pos1] = token * 2 + 1;
  }
}

// ---------------- prefix sums: row offsets + tile offsets -------------------
__global__ void prefix_kernel(const int* __restrict__ cnt,
                              int* __restrict__ expoff, int* __restrict__ toff)
{
  if (threadIdx.x == 0 && blockIdx.x == 0) {
    int s = 0, t = 0;
#pragma unroll
    for (int e = 0; e < NE; ++e) {
      expoff[e] = s;
      toff[e] = t;
      s += cnt[e];
      t += (cnt[e] + 255) >> 8;      // ceil(cnt/256) tiles
    }
    toff[NE] = t;
  }
}

// ---------------- fp32 -> bf16 of hidden states -----------------------------
__global__ __launch_bounds__(256) void convert_x_kernel(
    const float* __restrict__ X, unsigned short* __restrict__ Xb)
{
  const int i = blockIdx.x * 256 + threadIdx.x;
  const float4 v = ((const float4*)X)[i];
  short4v o;
  o.x = f2bf(v.x); o.y = f2bf(v.y); o.z = f2bf(v.z); o.w = f2bf(v.w);
  ((short4v*)Xb)[i] = o;
}

// ---------------- per-expert transpose fp32 [R][C] -> bf16 [C][R] -----------
// 64x64 tile, 256 threads, float4 in / short4 out, LDS-transposed staging.
__global__ __launch_bounds__(256) void transpose_bf16_kernel(
    const float* __restrict__ src, unsigned short* __restrict__ dst, int R, int C)
{
  __shared__ float tileT[64][68];      // stored transposed: [col][row]
  const int ez = blockIdx.z;
  src += (size_t)ez * R * C;
  dst += (size_t)ez * R * C;
  const int c0 = blockIdx.x * 64, r0 = blockIdx.y * 64;
  const int tid = threadIdx.x;
  const int cx = tid & 15;             // float4 column group
  const int ry = tid >> 4;             // 16 rows per pass
#pragma unroll
  for (int i = 0; i < 4; ++i) {
    const int row = ry + i * 16;
    const float4 v = *(const float4*)(src + (size_t)(r0 + row) * C + c0 + cx * 4);
    tileT[cx * 4 + 0][row] = v.x;
    tileT[cx * 4 + 1][row] = v.y;
    tileT[cx * 4 + 2][row] = v.z;
    tileT[cx * 4 + 3][row] = v.w;
  }
  __syncthreads();
#pragma unroll
  for (int i = 0; i < 4; ++i) {
    const int cc = ry + i * 16;        // dst row = c0+cc
    const float4 v = *(const float4*)(&tileT[cc][cx * 4]);
    short4v o;
    o.x = f2bf(v.x); o.y = f2bf(v.y); o.z = f2bf(v.z); o.w = f2bf(v.w);
    *(short4v*)(dst + (size_t)(c0 + cc) * R + r0 + cx * 4) = o;
  }
}

// ---------------- grouped expert GEMM, reg-staged double-buffered -----------
// LAYER 1: BM=256 BN=256 BK=64, K=1024 ; hmid[slot] = gelu(X[tok]@W1[e]+b1)
// LAYER 2: BM=256 BN=128 BK=64, K=4096 ; out[tok] += w*(hmid[slot]@W2[e]+b2)
// Staging: global_load_dwordx4 -> VGPR -> swizzled ds_write_b128 (no
// global_load_lds: its LDS dest must be wave-uniform; reg path is immune).
// Pipeline per K-tile kt: ds_write tile kt+1 (regs) -> issue loads kt+2 ->
// compute kt -> lgkmcnt(0); s_barrier. Loads stay in flight across barriers.
template<int LAYER>
__global__ __launch_bounds__(512, 2) void moe_gemm(
    const unsigned short* __restrict__ Abase,
    const unsigned short* __restrict__ Bt,
    const float* __restrict__ bias,
    const int* __restrict__ cnt,
    const int* __restrict__ expoff,
    const int* __restrict__ toff,
    const int* __restrict__ bucket,
    const float* __restrict__ pairw,
    unsigned short* __restrict__ hmid,
    float* __restrict__ out)
{
  constexpr int BM = 256, BN = (LAYER == 1) ? 256 : 128, BK = 64;
  constexpr int KDIM = (LAYER == 1) ? D_DIM : F_DIM;
  constexpr int NDIM = (LAYER == 1) ? F_DIM : D_DIM;
  constexpr int KT = KDIM / BK;
  constexpr int NT = NDIM / BN;              // 16 or 8 (grid: nt fastest)
  constexpr int NB = BN * BK * 2 / (512 * 16);   // B chunks/thread: 4 or 2
  constexpr int NFR = BN / 64;               // B frags/wave: 4 or 2
  constexpr int ASLOT = BM * BK * 2;         // 32 KiB
  constexpr int BSLOT = BN * BK * 2;         // 32 or 16 KiB

  // bijective XCD chunk swizzle (gridDim.x % 8 == 0 by construction)
  const int q = gridDim.x >> 3;
  const int g = (blockIdx.x & 7) * q + (blockIdx.x >> 3);
  const int mt_glob = g / NT;
  const int ntile = g % NT;
  if (mt_glob >= toff[NE]) return;
  int e = 0;
  while (mt_glob >= toff[e + 1]) ++e;
  const int mtile = mt_glob - toff[e];
  const int cnt_e = cnt[e];
  const int eoff = expoff[e];

  __shared__ __align__(16) char Alds[2][ASLOT];
  __shared__ __align__(16) char Blds[2][BSLOT];
  __shared__ int rowpair[BM];

  const int tid = threadIdx.x;
  const int lane = tid & 63;
  const int l15 = lane & 15, lhi = lane >> 4;
  const int wid = tid >> 6;
  const int wm = wid >> 2, wn = wid & 3;

  if (tid < BM) {
    int pos = mtile * BM + tid;
    rowpair[tid] = (pos < cnt_e) ? bucket[e * CAP + pos] : -1;
  }
  __syncthreads();

  // per-thread chunk ownership: chunk ci = i*512 + tid; row = ci>>3, col = ci&7
  // global read: plain (coalesced); LDS write addr: XOR-swizzled column.
  const unsigned short* a_src[4];
  int a_lw[4];
#pragma unroll
  for (int i = 0; i < 4; ++i) {
    int ci = i * 512 + tid;
    int r = ci >> 3, c = ci & 7;
    size_t arow;
    if (LAYER == 1) {
      int pair = rowpair[r];
      arow = (pair < 0) ? 0 : (size_t)(pair >> 1);
    } else {
      arow = (size_t)(eoff + mtile * BM + r);      // contiguous slot rows
    }
    a_src[i] = Abase + arow * KDIM + c * 8;
    a_lw[i] = r * 128 + ((c ^ (r & 7)) * 16);
  }
  const unsigned short* b_src[NB];
  int b_lw[NB];
#pragma unroll
  for (int i = 0; i < NB; ++i) {
    int ci = i * 512 + tid;
    int r = ci >> 3, c = ci & 7;
    int ng = ntile * BN + r;
    b_src[i] = Bt + (size_t)e * NDIM * KDIM + (size_t)ng * KDIM + c * 8;
    b_lw[i] = r * 128 + ((c ^ (r & 7)) * 16);
  }

  f32x4 acc[8][NFR];
#pragma unroll
  for (int m = 0; m < 8; ++m)
#pragma unroll
    for (int n = 0; n < NFR; ++n) acc[m][n] = (f32x4){0.f, 0.f, 0.f, 0.f};

  float4 ra[4], rb[NB];

  // prologue: tile0 -> regs -> buf0; tile1 -> regs
#pragma unroll
  for (int i = 0; i < 4; ++i) ra[i] = *(const float4*)(a_src[i]);
#pragma unroll
  for (int i = 0; i < NB; ++i) rb[i] = *(const float4*)(b_src[i]);
#pragma unroll
  for (int i = 0; i < 4; ++i) *(float4*)(&Alds[0][0] + a_lw[i]) = ra[i];
#pragma unroll
  for (int i = 0; i < NB; ++i) *(float4*)(&Blds[0][0] + b_lw[i]) = rb[i];
#pragma unroll
  for (int i = 0; i < 4; ++i) ra[i] = *(const float4*)(a_src[i] + BK);
#pragma unroll
  for (int i = 0; i < NB; ++i) rb[i] = *(const float4*)(b_src[i] + BK);
  asm volatile("s_waitcnt lgkmcnt(0)" ::: "memory");
  __builtin_amdgcn_sched_barrier(0);
  __builtin_amdgcn_s_barrier();

  for (int kt = 0; kt < KT; ++kt) {
    const int b = kt & 1;
    // ds_write tile kt+1 (regs) into the other buffer
    if (kt + 1 < KT) {
#pragma unroll
      for (int i = 0; i < 4; ++i) *(float4*)(&Alds[b ^ 1][0] + a_lw[i]) = ra[i];
#pragma unroll
      for (int i = 0; i < NB; ++i) *(float4*)(&Blds[b ^ 1][0] + b_lw[i]) = rb[i];
    }
    // issue tile kt+2 global loads (in flight through compute + barrier)
    if (kt + 2 < KT) {
#pragma unroll
      for (int i = 0; i < 4; ++i) ra[i] = *(const float4*)(a_src[i] + (kt + 2) * BK);
#pragma unroll
      for (int i = 0; i < NB; ++i) rb[i] = *(const float4*)(b_src[i] + (kt + 2) * BK);
    }
    // compute tile kt from buf[b]
    __builtin_amdgcn_s_setprio(1);
#pragma unroll
    for (int kk = 0; kk < 2; ++kk) {
      const int c16 = kk * 4 + lhi;
      short8 bfr[NFR];
#pragma unroll
      for (int n = 0; n < NFR; ++n) {
        int row = wn * (BN / 4) + n * 16 + l15;
        bfr[n] = *(const short8*)(&Blds[b][0] + row * 128 + ((c16 ^ (row & 7)) * 16));
      }
#pragma unroll
      for (int m = 0; m < 8; ++m) {
        int row = wm * 128 + m * 16 + l15;
        short8 af = *(const short8*)(&Alds[b][0] + row * 128 + ((c16 ^ (row & 7)) * 16));
#pragma unroll
        for (int n = 0; n < NFR; ++n)
          acc[m][n] = __builtin_amdgcn_mfma_f32_16x16x32_bf16(af, bfr[n], acc[m][n], 0, 0, 0);
      }
    }
    __builtin_amdgcn_s_setprio(0);
    asm volatile("s_waitcnt lgkmcnt(0)" ::: "memory");  // writes visible, reads done
    __builtin_amdgcn_sched_barrier(0);
    __builtin_amdgcn_s_barrier();
  }

  // epilogue: C/D layout col = lane&15, row = (lane>>4)*4 + j
#pragma unroll
  for (int m = 0; m < 8; ++m) {
#pragma unroll
    for (int j = 0; j < 4; ++j) {
      const int row = wm * 128 + m * 16 + lhi * 4 + j;
      const int pair = rowpair[row];
      if (pair < 0) continue;
#pragma unroll
      for (int n = 0; n < NFR; ++n) {
        const int col = ntile * BN + wn * (BN / 4) + n * 16 + l15;
        float val = acc[m][n][j] + bias[e * NDIM + col];
        if (LAYER == 1) {
          float gl = 0.5f * val * (1.f + erff(val * 0.70710678118654752f));
          hmid[(size_t)(eoff + mtile * BM + row) * F_DIM + col] =
              (unsigned short)f2bf(gl);
        } else {
          float y = val * pairw[pair];
          atomicAdd(out + ((size_t)(pair >> 1) * D_DIM + col), y);
        }
      }
    }
  }
}

// ---------------- launch ----------------------------------------------------
extern "C" void kernel_launch(void* const* d_in, const int* in_sizes, int n_in,
                              void* d_out, int out_size, void* d_ws, size_t ws_size,
                              hipStream_t stream)
{
  const float* X  = (const float*)d_in[0];
  const float* Wg = (const float*)d_in[1];
  const float* bg = (const float*)d_in[2];
  const float* W1 = (const float*)d_in[3];
  const float* b1 = (const float*)d_in[4];
  const float* W2 = (const float*)d_in[5];
  const float* b2 = (const float*)d_in[6];
  float* out = (float*)d_out;

  char* ws = (char*)d_ws;
  size_t off = 0;
  auto alloc = [&](size_t sz) {
    size_t o = off;
    off = (off + sz + 255) & ~(size_t)255;
    return o;
  };
  int*            cnt    = (int*)(ws + alloc(NE * sizeof(int)));
  int*            expoff = (int*)(ws + alloc(NE * sizeof(int)));
  int*            toff   = (int*)(ws + alloc((NE + 1) * sizeof(int)));
  int*            bucket = (int*)(ws + alloc((size_t)NE * CAP * sizeof(int)));
  float*          pairw  = (float*)(ws + alloc((size_t)N_TOK * 2 * sizeof(float)));
  unsigned short* Xb     = (unsigned short*)(ws + alloc((size_t)N_TOK * D_DIM * 2));
  unsigned short* W1t    = (unsigned short*)(ws + alloc((size_t)NE * D_DIM * F_DIM * 2));
  unsigned short* W2t    = (unsigned short*)(ws + alloc((size_t)NE * D_DIM * F_DIM * 2));
  unsigned short* hmid   = (unsigned short*)(ws + alloc((size_t)(N_TOK * 2 + 256) * F_DIM * 2));

  hipMemsetAsync(cnt, 0, NE * sizeof(int), stream);
  hipMemsetAsync(out, 0, (size_t)out_size * sizeof(float), stream);

  convert_x_kernel<<<N_TOK * D_DIM / 4 / 256, 256, 0, stream>>>(X, Xb);
  transpose_bf16_kernel<<<dim3(F_DIM / 64, D_DIM / 64, NE), 256, 0, stream>>>(
      W1, W1t, D_DIM, F_DIM);
  transpose_bf16_kernel<<<dim3(D_DIM / 64, F_DIM / 64, NE), 256, 0, stream>>>(
      W2, W2t, F_DIM, D_DIM);
  gate_kernel<<<N_TOK, 256, 0, stream>>>(X, Wg, bg, cnt, bucket, pairw);
  prefix_kernel<<<1, 64, 0, stream>>>(cnt, expoff, toff);

  // max tiles = sum_e ceil(cnt_e/256) <= (16384 + 8*255)/256 -> 71
  const int MAXT = 71;
  moe_gemm<1><<<MAXT * (F_DIM / 256), 512, 0, stream>>>(    // 1136 blocks (%8==0)
      Xb, W1t, b1, cnt, expoff, toff, bucket, pairw, hmid, out);
  moe_gemm<2><<<MAXT * (D_DIM / 128), 512, 0, stream>>>(    // 568 blocks (%8==0)
      hmid, W2t, b2, cnt, expoff, toff, bucket, pairw, hmid, out);
}

// Round 5
// 1098.717 us; speedup vs baseline: 1.2107x; 1.2107x over previous
//
#include <hip/hip_runtime.h>
#include <hip/hip_bf16.h>
#include <cstdint>
#include <math.h>

#define N_TOK 8192
#define D_DIM 1024
#define F_DIM 4096
#define NE 8
#define CAP 8192

typedef __attribute__((ext_vector_type(8))) short short8;
typedef __attribute__((ext_vector_type(4))) short short4v;
typedef __attribute__((ext_vector_type(4))) float f32x4;

__device__ __forceinline__ short f2bf(float f) {
  __bf16 b = (__bf16)f;
  return *(short*)&b;
}

// ---------------- gating: fp32 logits, top-2, renormalize, bucket scatter ----
__global__ __launch_bounds__(256) void gate_kernel(
    const float* __restrict__ X, const float* __restrict__ Wg,
    const float* __restrict__ bg, int* __restrict__ cnt,
    int* __restrict__ bucket, float* __restrict__ pairw)
{
  const int token = blockIdx.x;
  const int tid = threadIdx.x;
  const float4* x4 = (const float4*)(X + (size_t)token * D_DIM);
  const float4* wg4 = (const float4*)Wg;
  float part[NE];
#pragma unroll
  for (int e = 0; e < NE; ++e) part[e] = 0.f;
  {
    const float4 xv = x4[tid];                       // 256 thr x 4 = 1024
#pragma unroll
    for (int e = 0; e < NE; ++e) {
      const float4 wv = wg4[e * (D_DIM / 4) + tid];
      part[e] = fmaf(xv.x, wv.x, fmaf(xv.y, wv.y, fmaf(xv.z, wv.z, fmaf(xv.w, wv.w, part[e]))));
    }
  }
#pragma unroll
  for (int e = 0; e < NE; ++e) {
#pragma unroll
    for (int off = 32; off > 0; off >>= 1) part[e] += __shfl_down(part[e], off);
  }
  __shared__ float wsum[4][NE];
  const int wave = tid >> 6;
  if ((tid & 63) == 0) {
#pragma unroll
    for (int e = 0; e < NE; ++e) wsum[wave][e] = part[e];
  }
  __syncthreads();
  if (tid == 0) {
    float lg[NE];
#pragma unroll
    for (int e = 0; e < NE; ++e)
      lg[e] = wsum[0][e] + wsum[1][e] + wsum[2][e] + wsum[3][e] + bg[e];
    int e0 = 0;
#pragma unroll
    for (int e = 1; e < NE; ++e) if (lg[e] > lg[e0]) e0 = e;     // jax tie-break: lower idx
    int e1 = (e0 == 0) ? 1 : 0;
#pragma unroll
    for (int e = 0; e < NE; ++e) if (e != e0 && lg[e] > lg[e1]) e1 = e;
    float p1 = expf(lg[e1] - lg[e0]);            // p0 = 1; softmax denom cancels
    float inv = 1.f / (1.f + p1);
    pairw[token * 2]     = inv;
    pairw[token * 2 + 1] = p1 * inv;
    int pos0 = atomicAdd(&cnt[e0], 1);
    bucket[e0 * CAP + pos0] = token * 2;
    int pos1 = atomicAdd(&cnt[e1], 1);
    bucket[e1 * CAP + pos1] = token * 2 + 1;
  }
}

// ---------------- prefix sums: row offsets + tile offsets -------------------
__global__ void prefix_kernel(const int* __restrict__ cnt,
                              int* __restrict__ expoff, int* __restrict__ toff)
{
  if (threadIdx.x == 0 && blockIdx.x == 0) {
    int s = 0, t = 0;
#pragma unroll
    for (int e = 0; e < NE; ++e) {
      expoff[e] = s;
      toff[e] = t;
      s += cnt[e];
      t += (cnt[e] + 255) >> 8;      // ceil(cnt/256) tiles
    }
    toff[NE] = t;
  }
}

// ---------------- fp32 -> bf16 of hidden states -----------------------------
__global__ __launch_bounds__(256) void convert_x_kernel(
    const float* __restrict__ X, unsigned short* __restrict__ Xb)
{
  const int i = blockIdx.x * 256 + threadIdx.x;
  const float4 v = ((const float4*)X)[i];
  short4v o;
  o.x = f2bf(v.x); o.y = f2bf(v.y); o.z = f2bf(v.z); o.w = f2bf(v.w);
  ((short4v*)Xb)[i] = o;
}

// ---------------- per-expert transpose fp32 [R][C] -> bf16 [C][R] -----------
__global__ __launch_bounds__(256) void transpose_bf16_kernel(
    const float* __restrict__ src, unsigned short* __restrict__ dst, int R, int C)
{
  __shared__ float tileT[64][68];      // stored transposed: [col][row]
  const int ez = blockIdx.z;
  src += (size_t)ez * R * C;
  dst += (size_t)ez * R * C;
  const int c0 = blockIdx.x * 64, r0 = blockIdx.y * 64;
  const int tid = threadIdx.x;
  const int cx = tid & 15;             // float4 column group
  const int ry = tid >> 4;             // 16 rows per pass
#pragma unroll
  for (int i = 0; i < 4; ++i) {
    const int row = ry + i * 16;
    const float4 v = *(const float4*)(src + (size_t)(r0 + row) * C + c0 + cx * 4);
    tileT[cx * 4 + 0][row] = v.x;
    tileT[cx * 4 + 1][row] = v.y;
    tileT[cx * 4 + 2][row] = v.z;
    tileT[cx * 4 + 3][row] = v.w;
  }
  __syncthreads();
#pragma unroll
  for (int i = 0; i < 4; ++i) {
    const int cc = ry + i * 16;        // dst row = c0+cc
    const float4 v = *(const float4*)(&tileT[cc][cx * 4]);
    short4v o;
    o.x = f2bf(v.x); o.y = f2bf(v.y); o.z = f2bf(v.z); o.w = f2bf(v.w);
    *(short4v*)(dst + (size_t)(c0 + cc) * R + r0 + cx * 4) = o;
  }
}

// ---------------- grouped expert GEMM, reg-staged double-buffered -----------
// BM=256 BN=128 BK=64 both layers; 8 waves as 4M x 2N; per-wave 64x64 out ->
// acc[4][4] (64 VGPR). __launch_bounds__(512) (no min-wave clamp): 256-VGPR
// ceiling; LDS (97 KB) is the 1-block/CU limit anyway, so no occupancy cost.
// R4's spills (WRITE_SIZE 875 MB) came from the 128-VGPR cap vs ~200 demand.
// Pipeline per K-tile kt: ds_write kt+1 (regs) -> issue kt+2 loads -> MFMA kt
// -> lgkmcnt(0); s_barrier. Global loads stay in flight across barriers.
template<int LAYER>
__global__ __launch_bounds__(512) void moe_gemm(
    const unsigned short* __restrict__ Abase,
    const unsigned short* __restrict__ Bt,
    const float* __restrict__ bias,
    const int* __restrict__ cnt,
    const int* __restrict__ expoff,
    const int* __restrict__ toff,
    const int* __restrict__ bucket,
    const float* __restrict__ pairw,
    unsigned short* __restrict__ hmid,
    float* __restrict__ out)
{
  constexpr int BM = 256, BN = 128, BK = 64;
  constexpr int KDIM = (LAYER == 1) ? D_DIM : F_DIM;
  constexpr int NDIM = (LAYER == 1) ? F_DIM : D_DIM;
  constexpr int KT = KDIM / BK;
  constexpr int NT = NDIM / BN;              // 32 or 8 (grid: nt fastest)
  constexpr int ASLOT = BM * BK * 2;         // 32 KiB
  constexpr int BSLOT = BN * BK * 2;         // 16 KiB

  // bijective XCD chunk swizzle (gridDim.x % 8 == 0 by construction)
  const int q = gridDim.x >> 3;
  const int g = (blockIdx.x & 7) * q + (blockIdx.x >> 3);
  const int mt_glob = g / NT;
  const int ntile = g % NT;
  if (mt_glob >= toff[NE]) return;
  int e = 0;
  while (mt_glob >= toff[e + 1]) ++e;
  const int mtile = mt_glob - toff[e];
  const int cnt_e = cnt[e];
  const int eoff = expoff[e];

  __shared__ __align__(16) char Alds[2][ASLOT];   // 64 KiB
  __shared__ __align__(16) char Blds[2][BSLOT];   // 32 KiB
  __shared__ int rowpair[BM];

  const int tid = threadIdx.x;
  const int lane = tid & 63;
  const int l15 = lane & 15, lhi = lane >> 4;
  const int wid = tid >> 6;
  const int wm = wid >> 1, wn = wid & 1;          // 4M x 2N waves

  if (tid < BM) {
    int pos = mtile * BM + tid;
    rowpair[tid] = (pos < cnt_e) ? bucket[e * CAP + pos] : -1;
  }
  __syncthreads();

  // per-thread chunk: ci = i*512 + tid; row = ci>>3, col(16B) = ci&7.
  // global read: plain coalesced; LDS write: XOR-swizzled column.
  const unsigned short* a_src[4];
  int a_lw[4];
#pragma unroll
  for (int i = 0; i < 4; ++i) {
    int ci = i * 512 + tid;
    int r = ci >> 3, c = ci & 7;
    size_t arow;
    if (LAYER == 1) {
      int pair = rowpair[r];
      arow = (pair < 0) ? 0 : (size_t)(pair >> 1);
    } else {
      arow = (size_t)(eoff + mtile * BM + r);      // contiguous slot rows
    }
    a_src[i] = Abase + arow * KDIM + c * 8;
    a_lw[i] = r * 128 + ((c ^ (r & 7)) * 16);
  }
  const unsigned short* b_src[2];
  int b_lw[2];
#pragma unroll
  for (int i = 0; i < 2; ++i) {
    int ci = i * 512 + tid;
    int r = ci >> 3, c = ci & 7;
    int ng = ntile * BN + r;
    b_src[i] = Bt + (size_t)e * NDIM * KDIM + (size_t)ng * KDIM + c * 8;
    b_lw[i] = r * 128 + ((c ^ (r & 7)) * 16);
  }

  f32x4 acc[4][4];
#pragma unroll
  for (int m = 0; m < 4; ++m)
#pragma unroll
    for (int n = 0; n < 4; ++n) acc[m][n] = (f32x4){0.f, 0.f, 0.f, 0.f};

  float4 ra[4], rb[2];

  // prologue: tile0 -> regs -> buf0; tile1 -> regs
#pragma unroll
  for (int i = 0; i < 4; ++i) ra[i] = *(const float4*)(a_src[i]);
#pragma unroll
  for (int i = 0; i < 2; ++i) rb[i] = *(const float4*)(b_src[i]);
#pragma unroll
  for (int i = 0; i < 4; ++i) *(float4*)(&Alds[0][0] + a_lw[i]) = ra[i];
#pragma unroll
  for (int i = 0; i < 2; ++i) *(float4*)(&Blds[0][0] + b_lw[i]) = rb[i];
#pragma unroll
  for (int i = 0; i < 4; ++i) ra[i] = *(const float4*)(a_src[i] + BK);
#pragma unroll
  for (int i = 0; i < 2; ++i) rb[i] = *(const float4*)(b_src[i] + BK);
  asm volatile("s_waitcnt lgkmcnt(0)" ::: "memory");
  __builtin_amdgcn_sched_barrier(0);
  __builtin_amdgcn_s_barrier();

  for (int kt = 0; kt < KT; ++kt) {
    const int b = kt & 1;
    // ds_write tile kt+1 (regs) into the other buffer
    if (kt + 1 < KT) {
#pragma unroll
      for (int i = 0; i < 4; ++i) *(float4*)(&Alds[b ^ 1][0] + a_lw[i]) = ra[i];
#pragma unroll
      for (int i = 0; i < 2; ++i) *(float4*)(&Blds[b ^ 1][0] + b_lw[i]) = rb[i];
    }
    // issue tile kt+2 global loads (in flight through compute + barrier)
    if (kt + 2 < KT) {
#pragma unroll
      for (int i = 0; i < 4; ++i) ra[i] = *(const float4*)(a_src[i] + (kt + 2) * BK);
#pragma unroll
      for (int i = 0; i < 2; ++i) rb[i] = *(const float4*)(b_src[i] + (kt + 2) * BK);
    }
    // compute tile kt from buf[b]
    __builtin_amdgcn_s_setprio(1);
#pragma unroll
    for (int kk = 0; kk < 2; ++kk) {
      const int c16 = kk * 4 + lhi;
      short8 bfr[4];
#pragma unroll
      for (int n = 0; n < 4; ++n) {
        int row = wn * 64 + n * 16 + l15;
        bfr[n] = *(const short8*)(&Blds[b][0] + row * 128 + ((c16 ^ (row & 7)) * 16));
      }
#pragma unroll
      for (int m = 0; m < 4; ++m) {
        int row = wm * 64 + m * 16 + l15;
        short8 af = *(const short8*)(&Alds[b][0] + row * 128 + ((c16 ^ (row & 7)) * 16));
#pragma unroll
        for (int n = 0; n < 4; ++n)
          acc[m][n] = __builtin_amdgcn_mfma_f32_16x16x32_bf16(af, bfr[n], acc[m][n], 0, 0, 0);
      }
    }
    __builtin_amdgcn_s_setprio(0);
    asm volatile("s_waitcnt lgkmcnt(0)" ::: "memory");  // writes visible, reads done
    __builtin_amdgcn_sched_barrier(0);
    __builtin_amdgcn_s_barrier();
  }

  // epilogue: C/D layout col = lane&15, row = (lane>>4)*4 + j
#pragma unroll
  for (int m = 0; m < 4; ++m) {
#pragma unroll
    for (int j = 0; j < 4; ++j) {
      const int row = wm * 64 + m * 16 + lhi * 4 + j;
      const int pair = rowpair[row];
      if (pair < 0) continue;
#pragma unroll
      for (int n = 0; n < 4; ++n) {
        const int col = ntile * BN + wn * 64 + n * 16 + l15;
        float val = acc[m][n][j] + bias[e * NDIM + col];
        if (LAYER == 1) {
          float gl = 0.5f * val * (1.f + erff(val * 0.70710678118654752f));
          hmid[(size_t)(eoff + mtile * BM + row) * F_DIM + col] =
              (unsigned short)f2bf(gl);
        } else {
          float y = val * pairw[pair];
          atomicAdd(out + ((size_t)(pair >> 1) * D_DIM + col), y);
        }
      }
    }
  }
}

// ---------------- launch ----------------------------------------------------
extern "C" void kernel_launch(void* const* d_in, const int* in_sizes, int n_in,
                              void* d_out, int out_size, void* d_ws, size_t ws_size,
                              hipStream_t stream)
{
  const float* X  = (const float*)d_in[0];
  const float* Wg = (const float*)d_in[1];
  const float* bg = (const float*)d_in[2];
  const float* W1 = (const float*)d_in[3];
  const float* b1 = (const float*)d_in[4];
  const float* W2 = (const float*)d_in[5];
  const float* b2 = (const float*)d_in[6];
  float* out = (float*)d_out;

  char* ws = (char*)d_ws;
  size_t off = 0;
  auto alloc = [&](size_t sz) {
    size_t o = off;
    off = (off + sz + 255) & ~(size_t)255;
    return o;
  };
  int*            cnt    = (int*)(ws + alloc(NE * sizeof(int)));
  int*            expoff = (int*)(ws + alloc(NE * sizeof(int)));
  int*            toff   = (int*)(ws + alloc((NE + 1) * sizeof(int)));
  int*            bucket = (int*)(ws + alloc((size_t)NE * CAP * sizeof(int)));
  float*          pairw  = (float*)(ws + alloc((size_t)N_TOK * 2 * sizeof(float)));
  unsigned short* Xb     = (unsigned short*)(ws + alloc((size_t)N_TOK * D_DIM * 2));
  unsigned short* W1t    = (unsigned short*)(ws + alloc((size_t)NE * D_DIM * F_DIM * 2));
  unsigned short* W2t    = (unsigned short*)(ws + alloc((size_t)NE * D_DIM * F_DIM * 2));
  unsigned short* hmid   = (unsigned short*)(ws + alloc((size_t)(N_TOK * 2 + 256) * F_DIM * 2));

  hipMemsetAsync(cnt, 0, NE * sizeof(int), stream);
  hipMemsetAsync(out, 0, (size_t)out_size * sizeof(float), stream);

  convert_x_kernel<<<N_TOK * D_DIM / 4 / 256, 256, 0, stream>>>(X, Xb);
  transpose_bf16_kernel<<<dim3(F_DIM / 64, D_DIM / 64, NE), 256, 0, stream>>>(
      W1, W1t, D_DIM, F_DIM);
  transpose_bf16_kernel<<<dim3(D_DIM / 64, F_DIM / 64, NE), 256, 0, stream>>>(
      W2, W2t, F_DIM, D_DIM);
  gate_kernel<<<N_TOK, 256, 0, stream>>>(X, Wg, bg, cnt, bucket, pairw);
  prefix_kernel<<<1, 64, 0, stream>>>(cnt, expoff, toff);

  // max tiles = sum_e ceil(cnt_e/256) <= 71
  const int MAXT = 71;
  moe_gemm<1><<<MAXT * (F_DIM / 128), 512, 0, stream>>>(   // 2272 blocks (%8==0)
      Xb, W1t, b1, cnt, expoff, toff, bucket, pairw, hmid, out);
  moe_gemm<2><<<MAXT * (D_DIM / 128), 512, 0, stream>>>(   // 568 blocks (%8==0)
      hmid, W2t, b2, cnt, expoff, toff, bucket, pairw, hmid, out);
}

// Round 6
// 954.621 us; speedup vs baseline: 1.3934x; 1.1509x over previous
//
#include <hip/hip_runtime.h>
#include <hip/hip_bf16.h>
#include <cstdint>
#include <math.h>

#define N_TOK 8192
#define D_DIM 1024
#define F_DIM 4096
#define NE 8
#define CAP 8192
#define MAXT 72

typedef __attribute__((ext_vector_type(8))) short short8;
typedef __attribute__((ext_vector_type(4))) short short4v;
typedef __attribute__((ext_vector_type(4))) float f32x4;

__device__ __forceinline__ short f2bf(float f) {
  __bf16 b = (__bf16)f;
  return *(short*)&b;
}

// ---------------- gating: fp32 logits, top-2, renormalize, bucket scatter ----
__global__ __launch_bounds__(256) void gate_kernel(
    const float* __restrict__ X, const float* __restrict__ Wg,
    const float* __restrict__ bg, int* __restrict__ cnt,
    int* __restrict__ bucket, float* __restrict__ pairw)
{
  const int token = blockIdx.x;
  const int tid = threadIdx.x;
  const float4* x4 = (const float4*)(X + (size_t)token * D_DIM);
  const float4* wg4 = (const float4*)Wg;
  float part[NE];
#pragma unroll
  for (int e = 0; e < NE; ++e) part[e] = 0.f;
  {
    const float4 xv = x4[tid];
#pragma unroll
    for (int e = 0; e < NE; ++e) {
      const float4 wv = wg4[e * (D_DIM / 4) + tid];
      part[e] = fmaf(xv.x, wv.x, fmaf(xv.y, wv.y, fmaf(xv.z, wv.z, fmaf(xv.w, wv.w, part[e]))));
    }
  }
#pragma unroll
  for (int e = 0; e < NE; ++e) {
#pragma unroll
    for (int off = 32; off > 0; off >>= 1) part[e] += __shfl_down(part[e], off);
  }
  __shared__ float wsum[4][NE];
  const int wave = tid >> 6;
  if ((tid & 63) == 0) {
#pragma unroll
    for (int e = 0; e < NE; ++e) wsum[wave][e] = part[e];
  }
  __syncthreads();
  if (tid == 0) {
    float lg[NE];
#pragma unroll
    for (int e = 0; e < NE; ++e)
      lg[e] = wsum[0][e] + wsum[1][e] + wsum[2][e] + wsum[3][e] + bg[e];
    int e0 = 0;
#pragma unroll
    for (int e = 1; e < NE; ++e) if (lg[e] > lg[e0]) e0 = e;     // jax tie-break: lower idx
    int e1 = (e0 == 0) ? 1 : 0;
#pragma unroll
    for (int e = 0; e < NE; ++e) if (e != e0 && lg[e] > lg[e1]) e1 = e;
    float p1 = expf(lg[e1] - lg[e0]);            // p0 = 1; softmax denom cancels
    float inv = 1.f / (1.f + p1);
    pairw[token * 2]     = inv;
    pairw[token * 2 + 1] = p1 * inv;
    int pos0 = atomicAdd(&cnt[e0], 1);
    bucket[e0 * CAP + pos0] = token * 2;
    int pos1 = atomicAdd(&cnt[e1], 1);
    bucket[e1 * CAP + pos1] = token * 2 + 1;
  }
}

// ---------------- prefix sums: row offsets + tile offsets -------------------
__global__ void prefix_kernel(const int* __restrict__ cnt,
                              int* __restrict__ expoff, int* __restrict__ toff)
{
  if (threadIdx.x == 0 && blockIdx.x == 0) {
    int s = 0, t = 0;
#pragma unroll
    for (int e = 0; e < NE; ++e) {
      expoff[e] = s;
      toff[e] = t;
      s += cnt[e];
      t += (cnt[e] + 255) >> 8;      // ceil(cnt/256) tiles
    }
    toff[NE] = t;
  }
}

// ---------------- fp32 -> bf16 of hidden states -----------------------------
__global__ __launch_bounds__(256) void convert_x_kernel(
    const float* __restrict__ X, unsigned short* __restrict__ Xb)
{
  const int i = blockIdx.x * 256 + threadIdx.x;
  const float4 v = ((const float4*)X)[i];
  short4v o;
  o.x = f2bf(v.x); o.y = f2bf(v.y); o.z = f2bf(v.z); o.w = f2bf(v.w);
  ((short4v*)Xb)[i] = o;
}

// ---------------- per-expert transpose fp32 [R][C] -> bf16 [C][R] -----------
__global__ __launch_bounds__(256) void transpose_bf16_kernel(
    const float* __restrict__ src, unsigned short* __restrict__ dst, int R, int C)
{
  __shared__ float tileT[64][68];      // stored transposed: [col][row]
  const int ez = blockIdx.z;
  src += (size_t)ez * R * C;
  dst += (size_t)ez * R * C;
  const int c0 = blockIdx.x * 64, r0 = blockIdx.y * 64;
  const int tid = threadIdx.x;
  const int cx = tid & 15;
  const int ry = tid >> 4;
#pragma unroll
  for (int i = 0; i < 4; ++i) {
    const int row = ry + i * 16;
    const float4 v = *(const float4*)(src + (size_t)(r0 + row) * C + c0 + cx * 4);
    tileT[cx * 4 + 0][row] = v.x;
    tileT[cx * 4 + 1][row] = v.y;
    tileT[cx * 4 + 2][row] = v.z;
    tileT[cx * 4 + 3][row] = v.w;
  }
  __syncthreads();
#pragma unroll
  for (int i = 0; i < 4; ++i) {
    const int cc = ry + i * 16;
    const float4 v = *(const float4*)(&tileT[cc][cx * 4]);
    short4v o;
    o.x = f2bf(v.x); o.y = f2bf(v.y); o.z = f2bf(v.z); o.w = f2bf(v.w);
    *(short4v*)(dst + (size_t)(c0 + cc) * R + r0 + cx * 4) = o;
  }
}

// ---------------- grouped expert GEMM, 2-phase dbuf, DMA staging ------------
// LAYER 1: BM=256 BN=256; waves 2Mx4N; acc[8][4]. K=1024 (KT=16)
// LAYER 2: BM=256 BN=128; waves 4Mx2N; acc[4][4]. K=4096 (KT=64)
// Staging: global_load_lds width=16 with WAVE-UNIFORM LDS dest
// (readfirstlane(wid)-derived -> SGPR, no waterfall, no ds_write conflicts);
// per-lane GLOBAL source carries the inverse XOR swizzle so the swizzled
// ds_read_b128 fragment reads are bank-conflict-free (R1-R3: 0 conflicts).
// Schedule (T3 minimal 2-phase): stage kt+1 -> compute kt -> __syncthreads()
// (vmcnt drain lands ~1k cyc after issue -> L2 latency hidden).
template<int LAYER>
__global__ __launch_bounds__(512) void moe_gemm(
    const unsigned short* __restrict__ Abase,
    const unsigned short* __restrict__ Bt,
    const float* __restrict__ bias,
    const int* __restrict__ cnt,
    const int* __restrict__ expoff,
    const int* __restrict__ toff,
    const int* __restrict__ bucket,
    const float* __restrict__ pairw,
    unsigned short* __restrict__ hmid,
    float* __restrict__ out)
{
  constexpr int BM = 256, BN = (LAYER == 1) ? 256 : 128, BK = 64;
  constexpr int KDIM = (LAYER == 1) ? D_DIM : F_DIM;
  constexpr int NDIM = (LAYER == 1) ? F_DIM : D_DIM;
  constexpr int KT = KDIM / BK;
  constexpr int ANI = 4;                         // A stage insts/thread
  constexpr int BNI = BN * BK * 2 / (512 * 16);  // 4 or 2
  constexpr int WCOLS = (LAYER == 1) ? 4 : 2;
  constexpr int MSPAN = (LAYER == 1) ? 128 : 64; // per-wave M rows
  constexpr int MW = MSPAN / 16;                 // 8 or 4
  constexpr int NW = 4;                          // per-wave N frags (64 cols)

  // balanced decode: mt fastest (early-exit tiles spread across all XCDs),
  // XCD chunk = contiguous g-range -> B-panel L2 reuse within an XCD.
  const int q = gridDim.x >> 3;
  const int g = (blockIdx.x & 7) * q + (blockIdx.x >> 3);
  const int ntile = g / MAXT;
  const int mt_glob = g % MAXT;
  if (mt_glob >= toff[NE]) return;
  int e = 0;
  while (mt_glob >= toff[e + 1]) ++e;
  const int mtile = mt_glob - toff[e];
  const int cnt_e = cnt[e];
  const int eoff = expoff[e];

  __shared__ __align__(16) char Alds[2][BM * BK * 2];   // 64 KiB
  __shared__ __align__(16) char Blds[2][BN * BK * 2];   // 64 or 32 KiB
  __shared__ int rowpair[BM];

  const int tid = threadIdx.x;
  const int lane = tid & 63;
  const int l15 = lane & 15, lhi = lane >> 4;
  const int wid = tid >> 6;
  const int uw = __builtin_amdgcn_readfirstlane(wid);   // provably uniform
  const int wm = wid / WCOLS, wn = wid % WCOLS;

  if (tid < BM) {
    int pos = mtile * BM + tid;
    rowpair[tid] = (pos < cnt_e) ? bucket[e * CAP + pos] : -1;
  }
  __syncthreads();

  // chunk ci = i*512 + tid; r = ci>>3 (tile row), c = ci&7 (16B col).
  // LDS dest (uniform): (i*8 + uw)*1024 ; HW adds lane*16 -> linear layout.
  // global source column pre-XOR-swizzled: sc = c ^ (r&7).
  const unsigned short* a_src[ANI];
#pragma unroll
  for (int i = 0; i < ANI; ++i) {
    int ci = i * 512 + tid;
    int r = ci >> 3, c = ci & 7;
    int sc = c ^ (r & 7);
    size_t arow;
    if (LAYER == 1) {
      int pair = rowpair[r];
      arow = (pair < 0) ? 0 : (size_t)(pair >> 1);
    } else {
      arow = (size_t)(eoff + mtile * BM + r);          // contiguous slot rows
    }
    a_src[i] = Abase + arow * KDIM + sc * 8;
  }
  const unsigned short* b_src[BNI];
#pragma unroll
  for (int i = 0; i < BNI; ++i) {
    int ci = i * 512 + tid;
    int r = ci >> 3, c = ci & 7;
    int sc = c ^ (r & 7);
    int ng = ntile * BN + r;
    b_src[i] = Bt + (size_t)e * NDIM * KDIM + (size_t)ng * KDIM + sc * 8;
  }

  auto stage = [&](int buf, int kt) {
#pragma unroll
    for (int i = 0; i < ANI; ++i)
      __builtin_amdgcn_global_load_lds(
          (const __attribute__((address_space(1))) uint32_t*)(a_src[i] + kt * BK),
          (__attribute__((address_space(3))) uint32_t*)(&Alds[buf][0] + (i * 8 + uw) * 1024),
          16, 0, 0);
#pragma unroll
    for (int i = 0; i < BNI; ++i)
      __builtin_amdgcn_global_load_lds(
          (const __attribute__((address_space(1))) uint32_t*)(b_src[i] + kt * BK),
          (__attribute__((address_space(3))) uint32_t*)(&Blds[buf][0] + (i * 8 + uw) * 1024),
          16, 0, 0);
  };

  f32x4 acc[MW][NW];
#pragma unroll
  for (int m = 0; m < MW; ++m)
#pragma unroll
    for (int n = 0; n < NW; ++n) acc[m][n] = (f32x4){0.f, 0.f, 0.f, 0.f};

  stage(0, 0);
  __syncthreads();                                     // vmcnt(0) drain + barrier

  for (int kt = 0; kt < KT; ++kt) {
    const int b = kt & 1;
    if (kt + 1 < KT) stage(b ^ 1, kt + 1);             // in flight through compute
#pragma unroll
    for (int kk = 0; kk < 2; ++kk) {
      const int c16 = kk * 4 + lhi;
      short8 bfr[NW];
#pragma unroll
      for (int n = 0; n < NW; ++n) {
        int row = wn * 64 + n * 16 + l15;
        bfr[n] = *(const short8*)(&Blds[b][0] + row * 128 + ((c16 ^ (row & 7)) * 16));
      }
#pragma unroll
      for (int m = 0; m < MW; ++m) {
        int row = wm * MSPAN + m * 16 + l15;
        short8 af = *(const short8*)(&Alds[b][0] + row * 128 + ((c16 ^ (row & 7)) * 16));
#pragma unroll
        for (int n = 0; n < NW; ++n)
          acc[m][n] = __builtin_amdgcn_mfma_f32_16x16x32_bf16(af, bfr[n], acc[m][n], 0, 0, 0);
      }
    }
    __syncthreads();            // drains staging (issued ~1k cyc ago) + barrier
  }

  // epilogue: C/D layout col = lane&15, row = (lane>>4)*4 + j
#pragma unroll
  for (int m = 0; m < MW; ++m) {
#pragma unroll
    for (int j = 0; j < 4; ++j) {
      const int row = wm * MSPAN + m * 16 + lhi * 4 + j;
      const int pair = rowpair[row];
      if (pair < 0) continue;
#pragma unroll
      for (int n = 0; n < NW; ++n) {
        const int col = ntile * BN + wn * 64 + n * 16 + l15;
        float val = acc[m][n][j] + bias[e * NDIM + col];
        if (LAYER == 1) {
          float gl = 0.5f * val * (1.f + erff(val * 0.70710678118654752f));
          hmid[(size_t)(eoff + mtile * BM + row) * F_DIM + col] =
              (unsigned short)f2bf(gl);
        } else {
          float y = val * pairw[pair];
          atomicAdd(out + ((size_t)(pair >> 1) * D_DIM + col), y);
        }
      }
    }
  }
}

// ---------------- launch ----------------------------------------------------
extern "C" void kernel_launch(void* const* d_in, const int* in_sizes, int n_in,
                              void* d_out, int out_size, void* d_ws, size_t ws_size,
                              hipStream_t stream)
{
  const float* X  = (const float*)d_in[0];
  const float* Wg = (const float*)d_in[1];
  const float* bg = (const float*)d_in[2];
  const float* W1 = (const float*)d_in[3];
  const float* b1 = (const float*)d_in[4];
  const float* W2 = (const float*)d_in[5];
  const float* b2 = (const float*)d_in[6];
  float* out = (float*)d_out;

  char* ws = (char*)d_ws;
  size_t off = 0;
  auto alloc = [&](size_t sz) {
    size_t o = off;
    off = (off + sz + 255) & ~(size_t)255;
    return o;
  };
  int*            cnt    = (int*)(ws + alloc(NE * sizeof(int)));
  int*            expoff = (int*)(ws + alloc(NE * sizeof(int)));
  int*            toff   = (int*)(ws + alloc((NE + 1) * sizeof(int)));
  int*            bucket = (int*)(ws + alloc((size_t)NE * CAP * sizeof(int)));
  float*          pairw  = (float*)(ws + alloc((size_t)N_TOK * 2 * sizeof(float)));
  unsigned short* Xb     = (unsigned short*)(ws + alloc((size_t)N_TOK * D_DIM * 2));
  unsigned short* W1t    = (unsigned short*)(ws + alloc((size_t)NE * D_DIM * F_DIM * 2));
  unsigned short* W2t    = (unsigned short*)(ws + alloc((size_t)NE * D_DIM * F_DIM * 2));
  unsigned short* hmid   = (unsigned short*)(ws + alloc((size_t)(N_TOK * 2 + 256) * F_DIM * 2));

  hipMemsetAsync(cnt, 0, NE * sizeof(int), stream);
  hipMemsetAsync(out, 0, (size_t)out_size * sizeof(float), stream);

  convert_x_kernel<<<N_TOK * D_DIM / 4 / 256, 256, 0, stream>>>(X, Xb);
  transpose_bf16_kernel<<<dim3(F_DIM / 64, D_DIM / 64, NE), 256, 0, stream>>>(
      W1, W1t, D_DIM, F_DIM);
  transpose_bf16_kernel<<<dim3(D_DIM / 64, F_DIM / 64, NE), 256, 0, stream>>>(
      W2, W2t, F_DIM, D_DIM);
  gate_kernel<<<N_TOK, 256, 0, stream>>>(X, Wg, bg, cnt, bucket, pairw);
  prefix_kernel<<<1, 64, 0, stream>>>(cnt, expoff, toff);

  moe_gemm<1><<<MAXT * (F_DIM / 256), 512, 0, stream>>>(   // 1152 blocks (%8==0)
      Xb, W1t, b1, cnt, expoff, toff, bucket, pairw, hmid, out);
  moe_gemm<2><<<MAXT * (D_DIM / 128), 512, 0, stream>>>(   // 576 blocks (%8==0)
      hmid, W2t, b2, cnt, expoff, toff, bucket, pairw, hmid, out);
}

// Round 7
// 901.977 us; speedup vs baseline: 1.4748x; 1.0584x over previous
//
#include <hip/hip_runtime.h>
#include <hip/hip_bf16.h>
#include <cstdint>
#include <math.h>

#define N_TOK 8192
#define D_DIM 1024
#define F_DIM 4096
#define NE 8
#define CAP 8192
#define MAXT 136   // max sum_e ceil(cnt_e/128)

typedef __attribute__((ext_vector_type(8))) short short8;
typedef __attribute__((ext_vector_type(4))) short short4v;
typedef __attribute__((ext_vector_type(4))) float f32x4;

__device__ __forceinline__ short f2bf(float f) {
  __bf16 b = (__bf16)f;
  return *(short*)&b;
}
__device__ __forceinline__ float bf2f(short u) {
  union { unsigned int i; float f; } c;
  c.i = ((unsigned int)(unsigned short)u) << 16;
  return c.f;
}

// ---------------- gating + fused X->bf16 ------------------------------------
__global__ __launch_bounds__(256) void gate_kernel(
    const float* __restrict__ X, const float* __restrict__ Wg,
    const float* __restrict__ bg, int* __restrict__ cnt,
    int* __restrict__ bucket, float* __restrict__ pairw,
    unsigned short* __restrict__ Xb)
{
  const int token = blockIdx.x;
  const int tid = threadIdx.x;
  const float4* x4 = (const float4*)(X + (size_t)token * D_DIM);
  const float4* wg4 = (const float4*)Wg;
  float part[NE];
#pragma unroll
  for (int e = 0; e < NE; ++e) part[e] = 0.f;
  const float4 xv = x4[tid];
#pragma unroll
  for (int e = 0; e < NE; ++e) {
    const float4 wv = wg4[e * (D_DIM / 4) + tid];
    part[e] = fmaf(xv.x, wv.x, fmaf(xv.y, wv.y, fmaf(xv.z, wv.z, fmaf(xv.w, wv.w, part[e]))));
  }
  // fused bf16 convert of the hidden-state row
  short4v o;
  o.x = f2bf(xv.x); o.y = f2bf(xv.y); o.z = f2bf(xv.z); o.w = f2bf(xv.w);
  ((short4v*)(Xb + (size_t)token * D_DIM))[tid] = o;

#pragma unroll
  for (int e = 0; e < NE; ++e) {
#pragma unroll
    for (int off = 32; off > 0; off >>= 1) part[e] += __shfl_down(part[e], off);
  }
  __shared__ float wsum[4][NE];
  const int wave = tid >> 6;
  if ((tid & 63) == 0) {
#pragma unroll
    for (int e = 0; e < NE; ++e) wsum[wave][e] = part[e];
  }
  __syncthreads();
  if (tid == 0) {
    float lg[NE];
#pragma unroll
    for (int e = 0; e < NE; ++e)
      lg[e] = wsum[0][e] + wsum[1][e] + wsum[2][e] + wsum[3][e] + bg[e];
    int e0 = 0;
#pragma unroll
    for (int e = 1; e < NE; ++e) if (lg[e] > lg[e0]) e0 = e;     // jax tie-break: lower idx
    int e1 = (e0 == 0) ? 1 : 0;
#pragma unroll
    for (int e = 0; e < NE; ++e) if (e != e0 && lg[e] > lg[e1]) e1 = e;
    float p1 = expf(lg[e1] - lg[e0]);            // p0 = 1; softmax denom cancels
    float inv = 1.f / (1.f + p1);
    pairw[token * 2]     = inv;
    pairw[token * 2 + 1] = p1 * inv;
    int pos0 = atomicAdd(&cnt[e0], 1);
    bucket[e0 * CAP + pos0] = token * 2;
    int pos1 = atomicAdd(&cnt[e1], 1);
    bucket[e1 * CAP + pos1] = token * 2 + 1;
  }
}

// ---------------- prefix sums (row offsets + 128-row tile offsets) ----------
__global__ void prefix_kernel(const int* __restrict__ cnt,
                              int* __restrict__ expoff, int* __restrict__ toff)
{
  if (threadIdx.x == 0 && blockIdx.x == 0) {
    int s = 0, t = 0;
#pragma unroll
    for (int e = 0; e < NE; ++e) {
      expoff[e] = s;
      toff[e] = t;
      s += cnt[e];
      t += (cnt[e] + 127) >> 7;
    }
    toff[NE] = t;
  }
}

// ---------------- inverse map: pair -> slot ---------------------------------
__global__ __launch_bounds__(256) void fillslot_kernel(
    const int* __restrict__ cnt, const int* __restrict__ expoff,
    const int* __restrict__ bucket, int* __restrict__ pairslot)
{
  const int e = blockIdx.x;
  const int n = cnt[e], off = expoff[e];
  for (int p = threadIdx.x; p < n; p += 256)
    pairslot[bucket[e * CAP + p]] = off + p;
}

// ---------------- per-expert transpose fp32 [R][C] -> bf16 [C][R] -----------
__global__ __launch_bounds__(256) void transpose_bf16_kernel(
    const float* __restrict__ src, unsigned short* __restrict__ dst, int R, int C)
{
  __shared__ float tileT[64][68];
  const int ez = blockIdx.z;
  src += (size_t)ez * R * C;
  dst += (size_t)ez * R * C;
  const int c0 = blockIdx.x * 64, r0 = blockIdx.y * 64;
  const int tid = threadIdx.x;
  const int cx = tid & 15;
  const int ry = tid >> 4;
#pragma unroll
  for (int i = 0; i < 4; ++i) {
    const int row = ry + i * 16;
    const float4 v = *(const float4*)(src + (size_t)(r0 + row) * C + c0 + cx * 4);
    tileT[cx * 4 + 0][row] = v.x;
    tileT[cx * 4 + 1][row] = v.y;
    tileT[cx * 4 + 2][row] = v.z;
    tileT[cx * 4 + 3][row] = v.w;
  }
  __syncthreads();
#pragma unroll
  for (int i = 0; i < 4; ++i) {
    const int cc = ry + i * 16;
    const float4 v = *(const float4*)(&tileT[cc][cx * 4]);
    short4v o;
    o.x = f2bf(v.x); o.y = f2bf(v.y); o.z = f2bf(v.z); o.w = f2bf(v.w);
    *(short4v*)(dst + (size_t)(c0 + cc) * R + r0 + cx * 4) = o;
  }
}

// ---------------- grouped expert GEMM, 128x128, 2 blocks/CU -----------------
// LAYER 1: hmid[slot] = gelu(X[tok] @ W1[e] + b1)   (K=1024, N=4096, A gathered)
// LAYER 2: ybuf[slot] = hmid[slot] @ W2[e] + b2     (K=4096, N=1024, A dense)
// 4 waves (2M x 2N), per-wave 64x64, acc[4][4] (64 VGPR, no spills).
// LDS 64.5 KB -> 2 blocks/CU: cross-block overlap hides the per-K-tile drain.
// Staging: global_load_lds w16, uniform LDS dest, source column XOR-preswizzled
// so swizzled ds_read_b128 fragments are conflict-free (measured 0 conflicts).
template<int LAYER>
__global__ __launch_bounds__(256) void moe_gemm(
    const unsigned short* __restrict__ Abase,
    const unsigned short* __restrict__ Bt,
    const float* __restrict__ bias,
    const int* __restrict__ cnt,
    const int* __restrict__ expoff,
    const int* __restrict__ toff,
    const int* __restrict__ bucket,
    unsigned short* __restrict__ Obuf)      // hmid (L1) or ybuf (L2)
{
  constexpr int BM = 128, BN = 128, BK = 64;
  constexpr int KDIM = (LAYER == 1) ? D_DIM : F_DIM;
  constexpr int NDIM = (LAYER == 1) ? F_DIM : D_DIM;
  constexpr int KT = KDIM / BK;
  constexpr int SLOT = BM * BK * 2;          // 16 KiB

  // XCD chunk decode: ntile-major chunks (B-panel L2 reuse), mt fastest.
  const int q = gridDim.x >> 3;
  const int g = (blockIdx.x & 7) * q + (blockIdx.x >> 3);
  const int ntile = g / MAXT;
  const int mt_glob = g % MAXT;
  if (mt_glob >= toff[NE]) return;
  int e = 0;
  while (mt_glob >= toff[e + 1]) ++e;
  const int mtile = mt_glob - toff[e];
  const int cnt_e = cnt[e];
  const int eoff = expoff[e];

  __shared__ __align__(16) char Alds[2][SLOT];   // 32 KiB
  __shared__ __align__(16) char Blds[2][SLOT];   // 32 KiB
  __shared__ int rowpair[BM];

  const int tid = threadIdx.x;
  const int lane = tid & 63;
  const int l15 = lane & 15, lhi = lane >> 4;
  const int wid = tid >> 6;
  const int uw = __builtin_amdgcn_readfirstlane(wid);
  const int wm = wid >> 1, wn = wid & 1;

  if (LAYER == 1) {
    if (tid < BM) {
      int pos = mtile * BM + tid;
      rowpair[tid] = (pos < cnt_e) ? bucket[e * CAP + pos] : -1;
    }
    __syncthreads();
  }

  // chunk ci = i*256 + tid; r = ci>>3, c = ci&7 (16B col); src col preswizzled.
  const unsigned short* a_src[4];
  const unsigned short* b_src[4];
#pragma unroll
  for (int i = 0; i < 4; ++i) {
    int ci = i * 256 + tid;
    int r = ci >> 3, c = ci & 7;
    int sc = c ^ (r & 7);
    size_t arow;
    if (LAYER == 1) {
      int pair = rowpair[r];
      arow = (pair < 0) ? 0 : (size_t)(pair >> 1);
    } else {
      arow = (size_t)(eoff + mtile * BM + r);        // contiguous slot rows
    }
    a_src[i] = Abase + arow * KDIM + sc * 8;
    int ng = ntile * BN + r;
    b_src[i] = Bt + (size_t)e * NDIM * KDIM + (size_t)ng * KDIM + sc * 8;
  }

  auto stage = [&](int buf, int kt) {
#pragma unroll
    for (int i = 0; i < 4; ++i)
      __builtin_amdgcn_global_load_lds(
          (const __attribute__((address_space(1))) uint32_t*)(a_src[i] + kt * BK),
          (__attribute__((address_space(3))) uint32_t*)(&Alds[buf][0] + i * 4096 + uw * 1024),
          16, 0, 0);
#pragma unroll
    for (int i = 0; i < 4; ++i)
      __builtin_amdgcn_global_load_lds(
          (const __attribute__((address_space(1))) uint32_t*)(b_src[i] + kt * BK),
          (__attribute__((address_space(3))) uint32_t*)(&Blds[buf][0] + i * 4096 + uw * 1024),
          16, 0, 0);
  };

  f32x4 acc[4][4];
#pragma unroll
  for (int m = 0; m < 4; ++m)
#pragma unroll
    for (int n = 0; n < 4; ++n) acc[m][n] = (f32x4){0.f, 0.f, 0.f, 0.f};

  stage(0, 0);
  __syncthreads();

  for (int kt = 0; kt < KT; ++kt) {
    const int b = kt & 1;
    if (kt + 1 < KT) stage(b ^ 1, kt + 1);
#pragma unroll
    for (int kk = 0; kk < 2; ++kk) {
      const int c16 = kk * 4 + lhi;
      short8 bfr[4];
#pragma unroll
      for (int n = 0; n < 4; ++n) {
        int row = wn * 64 + n * 16 + l15;
        bfr[n] = *(const short8*)(&Blds[b][0] + row * 128 + ((c16 ^ (row & 7)) * 16));
      }
#pragma unroll
      for (int m = 0; m < 4; ++m) {
        int row = wm * 64 + m * 16 + l15;
        short8 af = *(const short8*)(&Alds[b][0] + row * 128 + ((c16 ^ (row & 7)) * 16));
#pragma unroll
        for (int n = 0; n < 4; ++n)
          acc[m][n] = __builtin_amdgcn_mfma_f32_16x16x32_bf16(af, bfr[n], acc[m][n], 0, 0, 0);
      }
    }
    __syncthreads();
  }

  // epilogue: C/D layout col = lane&15, row = (lane>>4)*4 + j; plain stores.
#pragma unroll
  for (int m = 0; m < 4; ++m) {
#pragma unroll
    for (int j = 0; j < 4; ++j) {
      const int row = wm * 64 + m * 16 + lhi * 4 + j;
      if (mtile * BM + row >= cnt_e) continue;
      const size_t slot = (size_t)(eoff + mtile * BM + row);
#pragma unroll
      for (int n = 0; n < 4; ++n) {
        const int col = ntile * BN + wn * 64 + n * 16 + l15;
        float val = acc[m][n][j] + bias[e * NDIM + col];
        if (LAYER == 1) {
          float gl = 0.5f * val * (1.f + erff(val * 0.70710678118654752f));
          Obuf[slot * F_DIM + col] = (unsigned short)f2bf(gl);
        } else {
          Obuf[slot * D_DIM + col] = (unsigned short)f2bf(val);
        }
      }
    }
  }
}

// ---------------- combine: out[t] = w0*y[slot0] + w1*y[slot1] ---------------
__global__ __launch_bounds__(256) void combine_kernel(
    const unsigned short* __restrict__ ybuf, const float* __restrict__ pairw,
    const int* __restrict__ pairslot, float* __restrict__ out)
{
  const int t = blockIdx.x;
  const int tid = threadIdx.x;
  const float w0 = pairw[t * 2], w1 = pairw[t * 2 + 1];
  const int s0 = pairslot[t * 2], s1 = pairslot[t * 2 + 1];
  const short4v a = ((const short4v*)(ybuf + (size_t)s0 * D_DIM))[tid];
  const short4v b = ((const short4v*)(ybuf + (size_t)s1 * D_DIM))[tid];
  float4 o;
  o.x = w0 * bf2f(a.x) + w1 * bf2f(b.x);
  o.y = w0 * bf2f(a.y) + w1 * bf2f(b.y);
  o.z = w0 * bf2f(a.z) + w1 * bf2f(b.z);
  o.w = w0 * bf2f(a.w) + w1 * bf2f(b.w);
  ((float4*)(out + (size_t)t * D_DIM))[tid] = o;
}

// ---------------- launch ----------------------------------------------------
extern "C" void kernel_launch(void* const* d_in, const int* in_sizes, int n_in,
                              void* d_out, int out_size, void* d_ws, size_t ws_size,
                              hipStream_t stream)
{
  const float* X  = (const float*)d_in[0];
  const float* Wg = (const float*)d_in[1];
  const float* bg = (const float*)d_in[2];
  const float* W1 = (const float*)d_in[3];
  const float* b1 = (const float*)d_in[4];
  const float* W2 = (const float*)d_in[5];
  const float* b2 = (const float*)d_in[6];
  float* out = (float*)d_out;

  char* ws = (char*)d_ws;
  size_t off = 0;
  auto alloc = [&](size_t sz) {
    size_t o = off;
    off = (off + sz + 255) & ~(size_t)255;
    return o;
  };
  int*            cnt      = (int*)(ws + alloc(NE * sizeof(int)));
  int*            expoff   = (int*)(ws + alloc(NE * sizeof(int)));
  int*            toff     = (int*)(ws + alloc((NE + 1) * sizeof(int)));
  int*            bucket   = (int*)(ws + alloc((size_t)NE * CAP * sizeof(int)));
  float*          pairw    = (float*)(ws + alloc((size_t)N_TOK * 2 * sizeof(float)));
  int*            pairslot = (int*)(ws + alloc((size_t)N_TOK * 2 * sizeof(int)));
  unsigned short* Xb       = (unsigned short*)(ws + alloc((size_t)N_TOK * D_DIM * 2));
  unsigned short* W1t      = (unsigned short*)(ws + alloc((size_t)NE * D_DIM * F_DIM * 2));
  unsigned short* W2t      = (unsigned short*)(ws + alloc((size_t)NE * D_DIM * F_DIM * 2));
  unsigned short* hmid     = (unsigned short*)(ws + alloc((size_t)(N_TOK * 2 + 256) * F_DIM * 2));
  unsigned short* ybuf     = W1t;   // W1t dead after GEMM1; ybuf written in GEMM2

  hipMemsetAsync(cnt, 0, NE * sizeof(int), stream);

  transpose_bf16_kernel<<<dim3(F_DIM / 64, D_DIM / 64, NE), 256, 0, stream>>>(
      W1, W1t, D_DIM, F_DIM);
  transpose_bf16_kernel<<<dim3(D_DIM / 64, F_DIM / 64, NE), 256, 0, stream>>>(
      W2, W2t, F_DIM, D_DIM);
  gate_kernel<<<N_TOK, 256, 0, stream>>>(X, Wg, bg, cnt, bucket, pairw, Xb);
  prefix_kernel<<<1, 64, 0, stream>>>(cnt, expoff, toff);
  fillslot_kernel<<<NE, 256, 0, stream>>>(cnt, expoff, bucket, pairslot);

  moe_gemm<1><<<MAXT * (F_DIM / 128), 256, 0, stream>>>(   // 4352 blocks (%8==0)
      Xb, W1t, b1, cnt, expoff, toff, bucket, hmid);
  moe_gemm<2><<<MAXT * (D_DIM / 128), 256, 0, stream>>>(   // 1088 blocks (%8==0)
      hmid, W2t, b2, cnt, expoff, toff, bucket, ybuf);
  combine_kernel<<<N_TOK, 256, 0, stream>>>(ybuf, pairw, pairslot, out);
}